// Round 5
// baseline (233.856 us; speedup 1.0000x reference)
//
#include <hip/hip_runtime.h>

typedef __fp16 f16;
typedef f16  h8 __attribute__((ext_vector_type(8)));
typedef float f4 __attribute__((ext_vector_type(4)));
typedef unsigned u32t;

#define NBLOCKS 1024
#define WPB 4
#define SPW 64
#define NBATCH 4
#define K2L 2.8853900817779268f   // 2*log2(e):  e^{2a} = 2^{K2L*a}

union H8u { h8 v; u32t u[4]; };
union U4h { uint4 u; h8 v; };

__device__ __forceinline__ u32t pk2(float a, float b) {
    return __builtin_bit_cast(u32t, __builtin_amdgcn_cvt_pkrtz(a, b));
}

// h = tanh(a), g = sech^2(a) given t = K2L*a (E = 2^t = e^{2a}); NaN-free at sat.
__device__ __forceinline__ void tanh_sech2_t(float t, float& h, float& g) {
    float E = __builtin_amdgcn_exp2f(t);
    float inv = __builtin_amdgcn_rcpf(E + 1.f);
    float u = inv + inv;
    h = 1.f - u;
    g = u * (2.f - u);
}

__global__ __launch_bounds__(256, 4) void pinn_mfma_kernel(
    const float* __restrict__ x_r, const float* __restrict__ sigma_r,
    const float* __restrict__ W1, const float* __restrict__ b1,
    const float* __restrict__ W2, const float* __restrict__ b2,
    const float* __restrict__ W3, const float* __restrict__ b3,
    const float* __restrict__ W4, float* __restrict__ out)
{
    // Pre-packed f16 A-fragments in frag layout: F[mat][frag=2*mt+kk][lane] = 4 u32.
    // mat 0: A2[m][k] = W2[k][m] (identity k-map). mat 1: A3 under pi3 so that the
    // L2 C->L3 B repack is same-lane pure-register (no exchange at all).
    __shared__ uint4 F[2][8][64];          // 16 KB
    __shared__ f4 Wk[64];                  // (K*w1x, K*w1y, K*w1z, K*b1)
    __shared__ f4 Wd[64];                  // (w1x, w1y, w1z, -2*Q1)
    __shared__ f4 BbK2[16], BbK3[16], W4v[16];

    const int tid = threadIdx.x, lane = tid & 63, wv = tid >> 6;
    const int sb = lane & 15;   // sample slot (B/C col)
    const int q  = lane >> 4;   // lane quarter

    if (tid < 64) {
        float wx = W1[tid], wy = W1[64 + tid], wz = W1[128 + tid];
        f4 a; a[0] = K2L * wx; a[1] = K2L * wy; a[2] = K2L * wz; a[3] = K2L * b1[tid];
        Wk[tid] = a;
        f4 d; d[0] = wx; d[1] = wy; d[2] = wz; d[3] = -2.f * (wx*wx + wy*wy + wz*wz);
        Wd[tid] = d;
        ((float*)BbK2)[tid] = K2L * b2[tid];
        ((float*)BbK3)[tid] = K2L * b3[tid];
        ((float*)W4v)[tid]  = W4[tid];
    }
    // Fill F: 1024 (mat,frag,lane) slots, 4 per thread (i uniform -> no divergence).
#pragma unroll
    for (int i = 0; i < 4; ++i) {
        const int slot = i * 256 + tid;
        const int mat = slot >> 9, fl = slot & 511;
        const int fg = fl >> 6, ln = fl & 63;
        const int mt = fg >> 1, kk = fg & 1;
        const int qq = ln >> 4, col = 16 * mt + (ln & 15);
        u32t v0, v1, v2, v3;
        if (mat == 0) {
            const int r0 = (32*kk + 8*qq) * 64 + col;
            v0 = pk2(W2[r0],       W2[r0 + 64]);
            v1 = pk2(W2[r0 + 128], W2[r0 + 192]);
            v2 = pk2(W2[r0 + 256], W2[r0 + 320]);
            v3 = pk2(W2[r0 + 384], W2[r0 + 448]);
        } else {
            // rows: 32*kk + 16*(p>>1) + 4*qq + 2*(p&1)  (+1)
            const int rb = (32*kk + 4*qq) * 64 + col;
            v0 = pk2(W3[rb],            W3[rb + 64]);
            v1 = pk2(W3[rb + 128],      W3[rb + 192]);
            v2 = pk2(W3[rb + 1024],     W3[rb + 1088]);
            v3 = pk2(W3[rb + 1152],     W3[rb + 1216]);
        }
        F[mat][fg][ln] = make_uint4(v0, v1, v2, v3);
    }
    __syncthreads();   // the only barrier

    const long sbase = ((long)blockIdx.x * WPB + wv) * SPW;
    float nx0 = x_r[(sbase + sb) * 3], nx1 = x_r[(sbase + sb) * 3 + 1],
          nx2 = x_r[(sbase + sb) * 3 + 2], nsg = sigma_r[sbase + sb];

#define MFMA5(MAT, Bhv, Bxv, Byv, Bzv, Bsv)                                               \
    _Pragma("unroll")                                                                     \
    for (int kk = 0; kk < 2; ++kk) {                                                      \
        U4h A; A.u = F[MAT][2 * mt + kk][lane];                                           \
        Ch = __builtin_amdgcn_mfma_f32_16x16x32_f16(A.v, Bhv[kk].v, Ch, 0, 0, 0);         \
        Cx = __builtin_amdgcn_mfma_f32_16x16x32_f16(A.v, Bxv[kk].v, Cx, 0, 0, 0);         \
        Cy = __builtin_amdgcn_mfma_f32_16x16x32_f16(A.v, Byv[kk].v, Cy, 0, 0, 0);         \
        Cz = __builtin_amdgcn_mfma_f32_16x16x32_f16(A.v, Bzv[kk].v, Cz, 0, 0, 0);         \
        Cs = __builtin_amdgcn_mfma_f32_16x16x32_f16(A.v, Bsv[kk].v, Cs, 0, 0, 0);         \
    }

#pragma unroll 1
    for (int t = 0; t < NBATCH; ++t) {
        const float x0 = nx0, x1 = nx1, x2 = nx2, sg = nsg;
        const long sn = sbase + ((t + 1) & 3) * 16 + sb;   // wraps on last iter (benign)
        nx0 = x_r[sn * 3]; nx1 = x_r[sn * 3 + 1]; nx2 = x_r[sn * 3 + 2];
        nsg = sigma_r[sn];

        // ---- layer 1 straight into B2 fragments (unit = 32kk+8q+2p+o) ----
        H8u Bh[2], Bx[2], By[2], Bz[2], Bs[2];
#pragma unroll
        for (int kk = 0; kk < 2; ++kk)
#pragma unroll
        for (int p = 0; p < 4; ++p) {
            float hv[2], xv[2], yv[2], zv[2], sv[2];
#pragma unroll
            for (int o = 0; o < 2; ++o) {
                const int u = 32 * kk + 8 * q + 2 * p + o;
                const f4 wk = Wk[u], wd = Wd[u];
                const float tt = fmaf(wk[0], x0, fmaf(wk[1], x1, fmaf(wk[2], x2, wk[3])));
                float h, g; tanh_sech2_t(tt, h, g);
                hv[o] = h; xv[o] = g * wd[0]; yv[o] = g * wd[1]; zv[o] = g * wd[2];
                sv[o] = (h * g) * wd[3];
            }
            Bh[kk].u[p] = pk2(hv[0], hv[1]); Bx[kk].u[p] = pk2(xv[0], xv[1]);
            By[kk].u[p] = pk2(yv[0], yv[1]); Bz[kk].u[p] = pk2(zv[0], zv[1]);
            Bs[kk].u[p] = pk2(sv[0], sv[1]);
        }

        // ---- layer 2: per-mt MFMA -> NL -> same-lane repack into B3 ----
        H8u Nh[2], Nx[2], Ny[2], Nz[2], Ns[2];
#pragma unroll
        for (int mt = 0; mt < 4; ++mt) {
            f4 Ch = {0,0,0,0}, Cx = {0,0,0,0}, Cy = {0,0,0,0},
               Cz = {0,0,0,0}, Cs = {0,0,0,0};
            MFMA5(0, Bh, Bx, By, Bz, Bs)
            const f4 bb = BbK2[4 * mt + q];
            const int ko = mt >> 1, po = 2 * (mt & 1);
            float oh[4], ox[4], oy[4], oz[4], os[4];
#pragma unroll
            for (int r = 0; r < 4; ++r) {
                float h, g; tanh_sech2_t(fmaf(Ch[r], K2L, bb[r]), h, g);
                const float ax = Cx[r], ay = Cy[r], az = Cz[r];
                const float qq = fmaf(ax, ax, fmaf(ay, ay, az * az));
                const float h2 = h + h;
                oh[r] = h; ox[r] = g * ax; oy[r] = g * ay; oz[r] = g * az;
                os[r] = g * fmaf(-h2, qq, Cs[r]);
            }
            Nh[ko].u[po] = pk2(oh[0], oh[1]); Nh[ko].u[po + 1] = pk2(oh[2], oh[3]);
            Nx[ko].u[po] = pk2(ox[0], ox[1]); Nx[ko].u[po + 1] = pk2(ox[2], ox[3]);
            Ny[ko].u[po] = pk2(oy[0], oy[1]); Ny[ko].u[po + 1] = pk2(oy[2], oy[3]);
            Nz[ko].u[po] = pk2(oz[0], oz[1]); Nz[ko].u[po + 1] = pk2(oz[2], oz[3]);
            Ns[ko].u[po] = pk2(os[0], os[1]); Ns[ko].u[po + 1] = pk2(os[2], os[3]);
        }

        // ---- layer 3 (A3 is pi3-permuted to match the repack) + W4 dot ----
        float tot = 0.f;
#pragma unroll
        for (int mt = 0; mt < 4; ++mt) {
            f4 Ch = {0,0,0,0}, Cx = {0,0,0,0}, Cy = {0,0,0,0},
               Cz = {0,0,0,0}, Cs = {0,0,0,0};
            MFMA5(1, Nh, Nx, Ny, Nz, Ns)
            const f4 bb = BbK3[4 * mt + q], w4 = W4v[4 * mt + q];
#pragma unroll
            for (int r = 0; r < 4; ++r) {
                float h, g; tanh_sech2_t(fmaf(Ch[r], K2L, bb[r]), h, g);
                const float ax = Cx[r], ay = Cy[r], az = Cz[r];
                const float qq = fmaf(ax, ax, fmaf(ay, ay, az * az));
                const float h2 = h + h;
                const float sv = g * fmaf(-h2, qq, Cs[r]);
                tot = fmaf(sv, w4[r], tot);
            }
        }
        tot += __shfl_xor(tot, 16);
        tot += __shfl_xor(tot, 32);
        if (lane < 16) out[sbase + t * 16 + sb] = sg * tot;
    }
}

extern "C" void kernel_launch(void* const* d_in, const int* in_sizes, int n_in,
                              void* d_out, int out_size, void* d_ws, size_t ws_size,
                              hipStream_t stream) {
    const float* x_r     = (const float*)d_in[0];
    const float* sigma_r = (const float*)d_in[1];
    const float* W1      = (const float*)d_in[2];
    const float* b1      = (const float*)d_in[3];
    const float* W2      = (const float*)d_in[4];
    const float* b2      = (const float*)d_in[5];
    const float* W3      = (const float*)d_in[6];
    const float* b3      = (const float*)d_in[7];
    const float* W4      = (const float*)d_in[8];
    float* out = (float*)d_out;

    pinn_mfma_kernel<<<NBLOCKS, 256, 0, stream>>>(
        x_r, sigma_r, W1, b1, W2, b2, W3, b3, W4, out);
}

// Round 6
// 152.959 us; speedup vs baseline: 1.5289x; 1.5289x over previous
//
#include <hip/hip_runtime.h>

typedef __fp16 f16;
typedef f16  h8 __attribute__((ext_vector_type(8)));
typedef float f4 __attribute__((ext_vector_type(4)));
typedef unsigned u32t;

#define NBLOCKS 1024
#define WPB 4
#define SPW 64
#define NBATCH 4
#define K2L 2.8853900817779268f   // 2*log2(e):  e^{2a} = 2^{K2L*a}

union H8u { h8 v; u32t u[4]; };
union U4h { uint4 u; h8 v; };

__device__ __forceinline__ u32t pk2(float a, float b) {
    return __builtin_bit_cast(u32t, __builtin_amdgcn_cvt_pkrtz(a, b));
}

// h = tanh(a), g = sech^2(a) given t = K2L*a (E = 2^t = e^{2a}); NaN-free at sat.
__device__ __forceinline__ void tanh_sech2_t(float t, float& h, float& g) {
    float E = __builtin_amdgcn_exp2f(t);
    float inv = __builtin_amdgcn_rcpf(E + 1.f);
    float u = inv + inv;
    h = 1.f - u;
    g = u * (2.f - u);
}

// NOTE: __launch_bounds__ min-waves/EU = 3 -> VGPR cap ~170. Demand here is
// ~140 live (B2 frags 40 + B3 frags 40 + C 20 + misc). Bounds=4 (cap 128)
// spilled everything to scratch: FETCH_SIZE 2.3MB -> 448MB, 5x slowdown (R5).
__global__ __launch_bounds__(256, 3) void pinn_mfma_kernel(
    const float* __restrict__ x_r, const float* __restrict__ sigma_r,
    const float* __restrict__ W1, const float* __restrict__ b1,
    const float* __restrict__ W2, const float* __restrict__ b2,
    const float* __restrict__ W3, const float* __restrict__ b3,
    const float* __restrict__ W4, float* __restrict__ out)
{
    // Pre-packed f16 A-fragments in frag layout: F[mat][frag=2*mt+kk][lane] = 4 u32.
    // mat 0: A2[m][k] = W2[k][m] (identity k-map). mat 1: A3 under pi3 so that the
    // L2 C->L3 B repack is same-lane pure-register (no exchange at all).
    __shared__ uint4 F[2][8][64];          // 16 KB
    __shared__ f4 Wk[64];                  // (K*w1x, K*w1y, K*w1z, K*b1)
    __shared__ f4 Wd[64];                  // (w1x, w1y, w1z, -2*Q1)
    __shared__ f4 BbK2[16], BbK3[16], W4v[16];

    const int tid = threadIdx.x, lane = tid & 63, wv = tid >> 6;
    const int sb = lane & 15;   // sample slot (B/C col)
    const int q  = lane >> 4;   // lane quarter

    if (tid < 64) {
        float wx = W1[tid], wy = W1[64 + tid], wz = W1[128 + tid];
        f4 a; a[0] = K2L * wx; a[1] = K2L * wy; a[2] = K2L * wz; a[3] = K2L * b1[tid];
        Wk[tid] = a;
        f4 d; d[0] = wx; d[1] = wy; d[2] = wz; d[3] = -2.f * (wx*wx + wy*wy + wz*wz);
        Wd[tid] = d;
        ((float*)BbK2)[tid] = K2L * b2[tid];
        ((float*)BbK3)[tid] = K2L * b3[tid];
        ((float*)W4v)[tid]  = W4[tid];
    }
    // Fill F: 1024 (mat,frag,lane) slots, 4 per thread (i uniform -> no divergence).
#pragma unroll
    for (int i = 0; i < 4; ++i) {
        const int slot = i * 256 + tid;
        const int mat = slot >> 9, fl = slot & 511;
        const int fg = fl >> 6, ln = fl & 63;
        const int mt = fg >> 1, kk = fg & 1;
        const int qq = ln >> 4, col = 16 * mt + (ln & 15);
        u32t v0, v1, v2, v3;
        if (mat == 0) {
            const int r0 = (32*kk + 8*qq) * 64 + col;
            v0 = pk2(W2[r0],       W2[r0 + 64]);
            v1 = pk2(W2[r0 + 128], W2[r0 + 192]);
            v2 = pk2(W2[r0 + 256], W2[r0 + 320]);
            v3 = pk2(W2[r0 + 384], W2[r0 + 448]);
        } else {
            // rows: 32*kk + 16*(p>>1) + 4*qq + 2*(p&1)  (+1)
            const int rb = (32*kk + 4*qq) * 64 + col;
            v0 = pk2(W3[rb],            W3[rb + 64]);
            v1 = pk2(W3[rb + 128],      W3[rb + 192]);
            v2 = pk2(W3[rb + 1024],     W3[rb + 1088]);
            v3 = pk2(W3[rb + 1152],     W3[rb + 1216]);
        }
        F[mat][fg][ln] = make_uint4(v0, v1, v2, v3);
    }
    __syncthreads();   // the only barrier

    const long sbase = ((long)blockIdx.x * WPB + wv) * SPW;
    float nx0 = x_r[(sbase + sb) * 3], nx1 = x_r[(sbase + sb) * 3 + 1],
          nx2 = x_r[(sbase + sb) * 3 + 2], nsg = sigma_r[sbase + sb];

#define MFMA5(MAT, Bhv, Bxv, Byv, Bzv, Bsv)                                               \
    _Pragma("unroll")                                                                     \
    for (int kk = 0; kk < 2; ++kk) {                                                      \
        U4h A; A.u = F[MAT][2 * mt + kk][lane];                                           \
        Ch = __builtin_amdgcn_mfma_f32_16x16x32_f16(A.v, Bhv[kk].v, Ch, 0, 0, 0);         \
        Cx = __builtin_amdgcn_mfma_f32_16x16x32_f16(A.v, Bxv[kk].v, Cx, 0, 0, 0);         \
        Cy = __builtin_amdgcn_mfma_f32_16x16x32_f16(A.v, Byv[kk].v, Cy, 0, 0, 0);         \
        Cz = __builtin_amdgcn_mfma_f32_16x16x32_f16(A.v, Bzv[kk].v, Cz, 0, 0, 0);         \
        Cs = __builtin_amdgcn_mfma_f32_16x16x32_f16(A.v, Bsv[kk].v, Cs, 0, 0, 0);         \
    }

#pragma unroll 1
    for (int t = 0; t < NBATCH; ++t) {
        const float x0 = nx0, x1 = nx1, x2 = nx2, sg = nsg;
        const long sn = sbase + ((t + 1) & 3) * 16 + sb;   // wraps on last iter (benign)
        nx0 = x_r[sn * 3]; nx1 = x_r[sn * 3 + 1]; nx2 = x_r[sn * 3 + 2];
        nsg = sigma_r[sn];

        // ---- layer 1 straight into B2 fragments (unit = 32kk+8q+2p+o) ----
        H8u Bh[2], Bx[2], By[2], Bz[2], Bs[2];
#pragma unroll
        for (int kk = 0; kk < 2; ++kk)
#pragma unroll
        for (int p = 0; p < 4; ++p) {
            float hv[2], xv[2], yv[2], zv[2], sv[2];
#pragma unroll
            for (int o = 0; o < 2; ++o) {
                const int u = 32 * kk + 8 * q + 2 * p + o;
                const f4 wk = Wk[u], wd = Wd[u];
                const float tt = fmaf(wk[0], x0, fmaf(wk[1], x1, fmaf(wk[2], x2, wk[3])));
                float h, g; tanh_sech2_t(tt, h, g);
                hv[o] = h; xv[o] = g * wd[0]; yv[o] = g * wd[1]; zv[o] = g * wd[2];
                sv[o] = (h * g) * wd[3];
            }
            Bh[kk].u[p] = pk2(hv[0], hv[1]); Bx[kk].u[p] = pk2(xv[0], xv[1]);
            By[kk].u[p] = pk2(yv[0], yv[1]); Bz[kk].u[p] = pk2(zv[0], zv[1]);
            Bs[kk].u[p] = pk2(sv[0], sv[1]);
        }

        // ---- layer 2: per-mt MFMA -> NL -> same-lane repack into B3 ----
        H8u Nh[2], Nx[2], Ny[2], Nz[2], Ns[2];
#pragma unroll
        for (int mt = 0; mt < 4; ++mt) {
            f4 Ch = {0,0,0,0}, Cx = {0,0,0,0}, Cy = {0,0,0,0},
               Cz = {0,0,0,0}, Cs = {0,0,0,0};
            MFMA5(0, Bh, Bx, By, Bz, Bs)
            const f4 bb = BbK2[4 * mt + q];
            const int ko = mt >> 1, po = 2 * (mt & 1);
            float oh[4], ox[4], oy[4], oz[4], os[4];
#pragma unroll
            for (int r = 0; r < 4; ++r) {
                float h, g; tanh_sech2_t(fmaf(Ch[r], K2L, bb[r]), h, g);
                const float ax = Cx[r], ay = Cy[r], az = Cz[r];
                const float qq = fmaf(ax, ax, fmaf(ay, ay, az * az));
                const float h2 = h + h;
                oh[r] = h; ox[r] = g * ax; oy[r] = g * ay; oz[r] = g * az;
                os[r] = g * fmaf(-h2, qq, Cs[r]);
            }
            Nh[ko].u[po] = pk2(oh[0], oh[1]); Nh[ko].u[po + 1] = pk2(oh[2], oh[3]);
            Nx[ko].u[po] = pk2(ox[0], ox[1]); Nx[ko].u[po + 1] = pk2(ox[2], ox[3]);
            Ny[ko].u[po] = pk2(oy[0], oy[1]); Ny[ko].u[po + 1] = pk2(oy[2], oy[3]);
            Nz[ko].u[po] = pk2(oz[0], oz[1]); Nz[ko].u[po + 1] = pk2(oz[2], oz[3]);
            Ns[ko].u[po] = pk2(os[0], os[1]); Ns[ko].u[po + 1] = pk2(os[2], os[3]);
        }

        // ---- layer 3 (A3 is pi3-permuted to match the repack) + W4 dot ----
        float tot = 0.f;
#pragma unroll
        for (int mt = 0; mt < 4; ++mt) {
            f4 Ch = {0,0,0,0}, Cx = {0,0,0,0}, Cy = {0,0,0,0},
               Cz = {0,0,0,0}, Cs = {0,0,0,0};
            MFMA5(1, Nh, Nx, Ny, Nz, Ns)
            const f4 bb = BbK3[4 * mt + q], w4 = W4v[4 * mt + q];
#pragma unroll
            for (int r = 0; r < 4; ++r) {
                float h, g; tanh_sech2_t(fmaf(Ch[r], K2L, bb[r]), h, g);
                const float ax = Cx[r], ay = Cy[r], az = Cz[r];
                const float qq = fmaf(ax, ax, fmaf(ay, ay, az * az));
                const float h2 = h + h;
                const float sv = g * fmaf(-h2, qq, Cs[r]);
                tot = fmaf(sv, w4[r], tot);
            }
        }
        tot += __shfl_xor(tot, 16);
        tot += __shfl_xor(tot, 32);
        if (lane < 16) out[sbase + t * 16 + sb] = sg * tot;
    }
}

extern "C" void kernel_launch(void* const* d_in, const int* in_sizes, int n_in,
                              void* d_out, int out_size, void* d_ws, size_t ws_size,
                              hipStream_t stream) {
    const float* x_r     = (const float*)d_in[0];
    const float* sigma_r = (const float*)d_in[1];
    const float* W1      = (const float*)d_in[2];
    const float* b1      = (const float*)d_in[3];
    const float* W2      = (const float*)d_in[4];
    const float* b2      = (const float*)d_in[5];
    const float* W3      = (const float*)d_in[6];
    const float* b3      = (const float*)d_in[7];
    const float* W4      = (const float*)d_in[8];
    float* out = (float*)d_out;

    pinn_mfma_kernel<<<NBLOCKS, 256, 0, stream>>>(
        x_r, sigma_r, W1, b1, W2, b2, W3, b3, W4, out);
}